// Round 6
// baseline (134.042 us; speedup 1.0000x reference)
//
#include <hip/hip_runtime.h>
#include <cmath>

#define NWALK 4096
#define NXD   48
#define HID   256
#define WPB   8
#define GCONST 0.7978845608028654f

typedef _Float16 half8   __attribute__((ext_vector_type(8)));
typedef float    float4v __attribute__((ext_vector_type(4)));

// ---------- prep_all: blocks 0..15: W2 transpose->fp16 + W1 cast; blocks 16..271: layer-1
// (unchanged, verified)
__global__ __launch_bounds__(256) void prep_all(const float* __restrict__ W2,
                                                const float* __restrict__ W1,
                                                const float* __restrict__ x,
                                                const float* __restrict__ b1,
                                                _Float16* __restrict__ W2c,
                                                _Float16* __restrict__ W1c,
                                                _Float16* __restrict__ t1h,
                                                _Float16* __restrict__ h1h,
                                                _Float16* __restrict__ ch) {
    __shared__ float tile[64][65];
    __shared__ float xs[16][NXD];

    if (blockIdx.x < 16) {
        const int bi = blockIdx.x & 3;
        const int bj = blockIdx.x >> 2;
        const int tx = threadIdx.x & 63;
        const int ty = threadIdx.x >> 6;
        #pragma unroll
        for (int r = 0; r < 16; ++r) {
            int il = ty * 16 + r;
            tile[tx][il] = W2[(bi * 64 + il) * HID + bj * 64 + tx];
        }
        __syncthreads();
        #pragma unroll
        for (int r = 0; r < 16; ++r) {
            int jl = ty * 16 + r;
            W2c[(bj * 64 + jl) * HID + bi * 64 + tx] = (_Float16)tile[jl][tx];
        }
        #pragma unroll
        for (int r = 0; r < 3; ++r) {
            int k = blockIdx.x * 3 + r;
            W1c[k * HID + threadIdx.x] = (_Float16)W1[k * HID + threadIdx.x];
        }
    } else {
        const int i  = threadIdx.x;
        const int w0 = (blockIdx.x - 16) * 16;

        float col[NXD];
        float S = 0.f;
        #pragma unroll
        for (int k = 0; k < NXD; ++k) {
            float v = W1[k * HID + i];
            col[k] = v;
            S = fmaf(v, v, S);
        }
        #pragma unroll
        for (int t = threadIdx.x; t < 16 * NXD; t += 256)
            ((float*)xs)[t] = x[w0 * NXD + t];
        __syncthreads();

        const float b = b1[i];
        #pragma unroll 4
        for (int w = 0; w < 16; ++w) {
            float a1 = b;
            #pragma unroll
            for (int k = 0; k < NXD; ++k)
                a1 = fmaf(xs[w][k], col[k], a1);
            float h1 = tanhf(a1);
            float t1 = 1.f - h1 * h1;
            int off = (w0 + w) * HID + i;
            t1h[off] = (_Float16)t1;
            h1h[off] = (_Float16)h1;
            ch[off]  = (_Float16)(S * h1 * t1);
        }
    }
}

// ---------- eloc8: in-register B fragments (W1c*t1 from L1), barrier-free main loop
__global__ __launch_bounds__(256, 2) void eloc8(
    const float* __restrict__ x,
    const float* __restrict__ b2,
    const float* __restrict__ w3,
    const _Float16* __restrict__ W2c,
    const _Float16* __restrict__ W1c,
    const _Float16* __restrict__ t1h,
    const _Float16* __restrict__ h1h,
    const _Float16* __restrict__ ch,
    float* __restrict__ out)
{
    __shared__ float xs[WPB][NXD];                        // 1536 B
    __shared__ float gw[WPB][4][NXD];                     // 6144 B (wave partials)
    __shared__ float rt1p[WPB][4][16];                    // 2048 B
    __shared__ float us[WPB][HID], uhs[WPB][HID];         // 16 KiB fp32
    __shared__ float b2s[HID], w3s[HID];                  // 2 KiB
    __shared__ float r2s[4][WPB];                         // 128 B
    __shared__ float rt2s[WPB];                           // 32 B

    const int w0   = blockIdx.x * WPB;
    const int tid  = threadIdx.x;
    const int wave = tid >> 6;          // 0..3
    const int lane = tid & 63;
    const int n16  = lane & 15;
    const int quad = (tid >> 4) & 3;    // 0..3

    // ---- full A-residency: 8 steps x 4 j-tiles = 128 regs (AGPR), loaded ONCE ----
    half8 afr[8][4];
    #pragma unroll
    for (int s = 0; s < 8; ++s)
        #pragma unroll
        for (int a = 0; a < 4; ++a)
            afr[s][a] = *(const half8*)(W2c + ((wave * 4 + a) * 16 + n16) * HID
                                        + s * 32 + quad * 8);

    b2s[tid] = b2[tid];
    w3s[tid] = w3[tid];
    #pragma unroll
    for (int t = tid; t < WPB * NXD; t += 256)
        ((float*)xs)[t] = x[w0 * NXD + t];

    // ---- prologue GEMM: a2 = W2^T h1 (even cols), p = W2^T c (odd cols)
    {
        const _Float16* src  = (n16 & 1) ? ch : h1h;
        const _Float16* brow = src + (size_t)(w0 + (n16 >> 1)) * HID;

        float4v acc[4];
        #pragma unroll
        for (int a = 0; a < 4; ++a) acc[a] = (float4v){0.f, 0.f, 0.f, 0.f};
        #pragma unroll
        for (int s = 0; s < 8; ++s) {
            half8 bf = *(const half8*)(brow + (s * 4 + quad) * 8);
            #pragma unroll
            for (int a = 0; a < 4; ++a)
                acc[a] = __builtin_amdgcn_mfma_f32_16x16x32_f16(afr[s][a], bf, acc[a], 0, 0, 0);
        }

        __syncthreads();   // b2s/w3s visible

        const int w = n16 >> 1;
        float um[4][4];
        #pragma unroll
        for (int a = 0; a < 4; ++a)
            #pragma unroll
            for (int reg = 0; reg < 4; ++reg) um[a][reg] = 0.f;

        if (!(n16 & 1)) {  // even columns hold a2 -> activation, u/uh2 to LDS
            #pragma unroll
            for (int a = 0; a < 4; ++a)
                #pragma unroll
                for (int reg = 0; reg < 4; ++reg) {
                    int i    = (wave * 4 + a) * 16 + quad * 4 + reg;
                    float a2 = acc[a][reg] + b2s[i];
                    float h2 = tanhf(a2);
                    float t2 = 1.f - h2 * h2;
                    float u  = w3s[i] * t2;
                    um[a][reg] = u;
                    us [w][i] = u;
                    uhs[w][i] = u * h2;
                }
        }

        // rt2 = sum_i u_i * p_i : odd columns hold p; pull u from even neighbor
        float part = 0.f;
        #pragma unroll
        for (int a = 0; a < 4; ++a)
            #pragma unroll
            for (int reg = 0; reg < 4; ++reg) {
                float uo = __shfl_xor(um[a][reg], 1, 64);
                part = fmaf(uo, acc[a][reg], part);
            }
        part += __shfl_xor(part, 16, 64);
        part += __shfl_xor(part, 32, 64);
        if (quad == 0 && (n16 & 1)) r2s[wave][w] = part;
    }
    __syncthreads();
    if (tid < WPB)
        rt2s[tid] = r2s[0][tid] + r2s[1][tid] + r2s[2][tid] + r2s[3][tid];
    __syncthreads();   // us/uhs, rt2s ready — NO further barriers until final combine

    #pragma unroll 1
    for (int ww = 0; ww < WPB; ++ww) {
        const int wg = w0 + ww;

        // t1 fragments for this walker: chunk (s*4+quad), krow-independent (global, L2-hot)
        half8 t1f[8];
        #pragma unroll
        for (int s = 0; s < 8; ++s)
            t1f[s] = *(const half8*)(t1h + (size_t)wg * HID + (s * 4 + quad) * 8);

        // u fold operands: 4 broadcast b128 reads (16 regs)
        float4v uu[4];
        #pragma unroll
        for (int a = 0; a < 4; ++a)
            uu[a] = *(const float4v*)(&us[ww][(wave * 4 + a) * 16 + quad * 4]);

        // deferred-rt1 accumulator
        float4v sq[4];
        #pragma unroll
        for (int a = 0; a < 4; ++a) sq[a] = (float4v){0.f, 0.f, 0.f, 0.f};

        #pragma unroll 1
        for (int kt = 0; kt < 3; ++kt) {
            const int krow = kt * 16 + n16;
            const _Float16* wrow = W1c + krow * HID;

            // W1c fragments from L1 (24 KB, resident); no LDS, no swizzle
            half8 w1v[8];
            #pragma unroll
            for (int s = 0; s < 8; ++s)
                w1v[s] = *(const half8*)(wrow + (s * 4 + quad) * 8);

            float4v acc[4];
            #pragma unroll
            for (int a = 0; a < 4; ++a) acc[a] = (float4v){0.f, 0.f, 0.f, 0.f};

            __builtin_amdgcn_s_setprio(1);
            #pragma unroll
            for (int s = 0; s < 8; ++s) {
                half8 bf = w1v[s] * t1f[s];   // bitwise-identical to staged AsT product
                #pragma unroll
                for (int a = 0; a < 4; ++a)
                    acc[a] = __builtin_amdgcn_mfma_f32_16x16x32_f16(
                        afr[s][a], bf, acc[a], 0, 0, 0);
            }
            __builtin_amdgcn_s_setprio(0);

            float g = 0.f;
            #pragma unroll
            for (int a = 0; a < 4; ++a)
                #pragma unroll
                for (int reg = 0; reg < 4; ++reg) {
                    float m = acc[a][reg];
                    sq[a][reg] = fmaf(m, m, sq[a][reg]);
                    g          = fmaf(m, uu[a][reg], g);
                }
            g += __shfl_xor(g, 16, 64);
            g += __shfl_xor(g, 32, 64);
            if (lane < 16) gw[ww][wave][kt * 16 + lane] = g;
        }

        // rt1 contraction: load uh now (4 b128), fold against sq
        float rt1 = 0.f;
        #pragma unroll
        for (int a = 0; a < 4; ++a) {
            float4v uh = *(const float4v*)(&uhs[ww][(wave * 4 + a) * 16 + quad * 4]);
            #pragma unroll
            for (int reg = 0; reg < 4; ++reg)
                rt1 = fmaf(sq[a][reg], uh[reg], rt1);
        }
        rt1 += __shfl_xor(rt1, 16, 64);
        rt1 += __shfl_xor(rt1, 32, 64);
        if (lane < 16) rt1p[ww][wave][lane] = rt1;
        // no barrier: each wave writes only its own gw/rt1p slices
    }

    __syncthreads();   // all gw/rt1p durable

    // ---- deferred final combine: wave handles walkers 2*wave, 2*wave+1 ----
    const int wa = 2 * wave, wb = wa + 1;
    float rt2a = rt2s[wa];
    float rt2b = rt2s[wb];

    float r0 = rt1p[wa][quad][n16];
    float r1 = rt1p[wb][quad][n16];

    float ga = 0.f, gb = 0.f, xa = 0.f, xb = 0.f;
    if (lane < NXD) {
        ga = gw[wa][0][lane] + gw[wa][1][lane] + gw[wa][2][lane] + gw[wa][3][lane];
        gb = gw[wb][0][lane] + gw[wb][1][lane] + gw[wb][2][lane] + gw[wb][3][lane];
        xa = xs[wa][lane];
        xb = xs[wb][lane];
    }
    float gga = ga * ga, ggb = gb * gb;
    float pa = 0.5f * xa * xa, pb = 0.5f * xb * xb;
    #pragma unroll
    for (int off = 32; off > 0; off >>= 1) {
        r0  += __shfl_down(r0,  off, 64);
        r1  += __shfl_down(r1,  off, 64);
        gga += __shfl_down(gga, off, 64);
        ggb += __shfl_down(ggb, off, 64);
        pa  += __shfl_down(pa,  off, 64);
        pb  += __shfl_down(pb,  off, 64);
    }
    if (lane == 0) {
        float kina = r0 + rt2a - 0.5f * gga;
        float kinb = r1 + rt2b - 0.5f * ggb;

        float x0 = xs[wa][0], x1 = xs[wa][1], x2 = xs[wa][2];
        float x3 = xs[wa][3], x4 = xs[wa][4], x5 = xs[wa][5];
        float d01 = (x0-x1)*(x0-x1) + (x2-x1)*(x2-x1);
        float d02 = (x0-x2)*(x0-x2) + (x1-x2)*(x1-x2);
        float d12 = (x3-x5)*(x3-x5) + (x4-x5)*(x4-x5);
        float intera = GCONST * (expf(-2.f*d01) + expf(-2.f*d02) + expf(-2.f*d12));

        x0 = xs[wb][0]; x1 = xs[wb][1]; x2 = xs[wb][2];
        x3 = xs[wb][3]; x4 = xs[wb][4]; x5 = xs[wb][5];
        float e01 = (x0-x1)*(x0-x1) + (x2-x1)*(x2-x1);
        float e02 = (x0-x2)*(x0-x2) + (x1-x2)*(x1-x2);
        float e12 = (x3-x5)*(x3-x5) + (x4-x5)*(x4-x5);
        float interb = GCONST * (expf(-2.f*e01) + expf(-2.f*e02) + expf(-2.f*e12));

        const int wga = w0 + wa, wgb = w0 + wb;
        out[wga]             = kina + pa + intera;
        out[NWALK + wga]     = kina;
        out[2 * NWALK + wga] = pa;
        out[3 * NWALK + wga] = intera;
        out[wgb]             = kinb + pb + interb;
        out[NWALK + wgb]     = kinb;
        out[2 * NWALK + wgb] = pb;
        out[3 * NWALK + wgb] = interb;
    }
}

extern "C" void kernel_launch(void* const* d_in, const int* in_sizes, int n_in,
                              void* d_out, int out_size, void* d_ws, size_t ws_size,
                              hipStream_t stream) {
    const float* x  = (const float*)d_in[0];
    const float* W1 = (const float*)d_in[1];
    const float* b1 = (const float*)d_in[2];
    const float* W2 = (const float*)d_in[3];
    const float* b2 = (const float*)d_in[4];
    const float* w3 = (const float*)d_in[5];
    float* out = (float*)d_out;

    char* ws = (char*)d_ws;
    _Float16* W2c = (_Float16*)(ws);                       // 128 KB
    _Float16* W1c = (_Float16*)(ws + 131072);              // 24 KB
    _Float16* t1h = (_Float16*)(ws + 155648);              // 2 MB
    _Float16* h1h = (_Float16*)(ws + 2252800);             // 2 MB
    _Float16* chv = (_Float16*)(ws + 4349952);             // 2 MB

    prep_all<<<16 + NWALK / 16, 256, 0, stream>>>(W2, W1, x, b1, W2c, W1c, t1h, h1h, chv);
    eloc8<<<NWALK / WPB, 256, 0, stream>>>(x, b2, w3, W2c, W1c, t1h, h1h, chv, out);
}

// Round 7
// 110.350 us; speedup vs baseline: 1.2147x; 1.2147x over previous
//
#include <hip/hip_runtime.h>
#include <cmath>

#define NWALK 4096
#define NXD   48
#define HID   256
#define WPB   8
#define GCONST 0.7978845608028654f

typedef _Float16 half8   __attribute__((ext_vector_type(8)));
typedef float    float4v __attribute__((ext_vector_type(4)));

// ---------- prep_all: blocks 0..15: W2 transpose->fp16 + W1 cast; blocks 16..271: layer-1
// (unchanged, verified)
__global__ __launch_bounds__(256) void prep_all(const float* __restrict__ W2,
                                                const float* __restrict__ W1,
                                                const float* __restrict__ x,
                                                const float* __restrict__ b1,
                                                _Float16* __restrict__ W2c,
                                                _Float16* __restrict__ W1c,
                                                _Float16* __restrict__ t1h,
                                                _Float16* __restrict__ h1h,
                                                _Float16* __restrict__ ch) {
    __shared__ float tile[64][65];
    __shared__ float xs[16][NXD];

    if (blockIdx.x < 16) {
        const int bi = blockIdx.x & 3;
        const int bj = blockIdx.x >> 2;
        const int tx = threadIdx.x & 63;
        const int ty = threadIdx.x >> 6;
        #pragma unroll
        for (int r = 0; r < 16; ++r) {
            int il = ty * 16 + r;
            tile[tx][il] = W2[(bi * 64 + il) * HID + bj * 64 + tx];
        }
        __syncthreads();
        #pragma unroll
        for (int r = 0; r < 16; ++r) {
            int jl = ty * 16 + r;
            W2c[(bj * 64 + jl) * HID + bi * 64 + tx] = (_Float16)tile[jl][tx];
        }
        #pragma unroll
        for (int r = 0; r < 3; ++r) {
            int k = blockIdx.x * 3 + r;
            W1c[k * HID + threadIdx.x] = (_Float16)W1[k * HID + threadIdx.x];
        }
    } else {
        const int i  = threadIdx.x;
        const int w0 = (blockIdx.x - 16) * 16;

        float col[NXD];
        float S = 0.f;
        #pragma unroll
        for (int k = 0; k < NXD; ++k) {
            float v = W1[k * HID + i];
            col[k] = v;
            S = fmaf(v, v, S);
        }
        #pragma unroll
        for (int t = threadIdx.x; t < 16 * NXD; t += 256)
            ((float*)xs)[t] = x[w0 * NXD + t];
        __syncthreads();

        const float b = b1[i];
        #pragma unroll 4
        for (int w = 0; w < 16; ++w) {
            float a1 = b;
            #pragma unroll
            for (int k = 0; k < NXD; ++k)
                a1 = fmaf(xs[w][k], col[k], a1);
            float h1 = tanhf(a1);
            float t1 = 1.f - h1 * h1;
            int off = (w0 + w) * HID + i;
            t1h[off] = (_Float16)t1;
            h1h[off] = (_Float16)h1;
            ch[off]  = (_Float16)(S * h1 * t1);
        }
    }
}

// ---------- eloc8: walker-invariant W1 in LDS (swizzled), t1 applied in registers,
//                  barrier-free main loop (no staging, no ds_writes)
__global__ __launch_bounds__(256, 2) void eloc8(
    const float* __restrict__ x,
    const float* __restrict__ b2,
    const float* __restrict__ w3,
    const _Float16* __restrict__ W2c,
    const _Float16* __restrict__ W1c,
    const _Float16* __restrict__ t1h,
    const _Float16* __restrict__ h1h,
    const _Float16* __restrict__ ch,
    float* __restrict__ out)
{
    __shared__ __align__(16) _Float16 W1s[48 * HID];      // 24 KiB, swizzled, walker-invariant
    __shared__ float xs[WPB][NXD];                        // 1536 B
    __shared__ float gw[WPB][4][NXD];                     // 6144 B (wave partials)
    __shared__ float rt1p[WPB][4][16];                    // 2048 B
    __shared__ float us[WPB][HID], uhs[WPB][HID];         // 16 KiB fp32
    __shared__ float b2s[HID], w3s[HID];                  // 2 KiB
    __shared__ float r2s[4][WPB];                         // 128 B
    __shared__ float rt2s[WPB];                           // 32 B

    const int w0   = blockIdx.x * WPB;
    const int tid  = threadIdx.x;
    const int wave = tid >> 6;          // 0..3
    const int lane = tid & 63;
    const int n16  = lane & 15;
    const int quad = (tid >> 4) & 3;    // 0..3

    // ---- full A-residency: 8 steps x 4 j-tiles = 128 regs (AGPR), loaded ONCE ----
    half8 afr[8][4];
    #pragma unroll
    for (int s = 0; s < 8; ++s)
        #pragma unroll
        for (int a = 0; a < 4; ++a)
            afr[s][a] = *(const half8*)(W2c + ((wave * 4 + a) * 16 + n16) * HID
                                        + s * 32 + quad * 8);

    b2s[tid] = b2[tid];
    w3s[tid] = w3[tid];
    #pragma unroll
    for (int t = tid; t < WPB * NXD; t += 256)
        ((float*)xs)[t] = x[w0 * NXD + t];

    // ---- W1s fill: swizzled exactly like the old AsT (write chunk c at c^(k&7)) ----
    #pragma unroll
    for (int t = tid; t < 48 * 32; t += 256) {
        int k = t >> 5, c = t & 31;
        half8 wv = *(const half8*)(W1c + k * HID + c * 8);
        *(half8*)(W1s + k * HID + ((c ^ (k & 7)) * 8)) = wv;
    }

    // ---- prologue GEMM: a2 = W2^T h1 (even cols), p = W2^T c (odd cols)
    {
        const _Float16* src  = (n16 & 1) ? ch : h1h;
        const _Float16* brow = src + (size_t)(w0 + (n16 >> 1)) * HID;

        float4v acc[4];
        #pragma unroll
        for (int a = 0; a < 4; ++a) acc[a] = (float4v){0.f, 0.f, 0.f, 0.f};
        #pragma unroll
        for (int s = 0; s < 8; ++s) {
            half8 bf = *(const half8*)(brow + (s * 4 + quad) * 8);
            #pragma unroll
            for (int a = 0; a < 4; ++a)
                acc[a] = __builtin_amdgcn_mfma_f32_16x16x32_f16(afr[s][a], bf, acc[a], 0, 0, 0);
        }

        __syncthreads();   // b2s/w3s visible

        const int w = n16 >> 1;
        float um[4][4];
        #pragma unroll
        for (int a = 0; a < 4; ++a)
            #pragma unroll
            for (int reg = 0; reg < 4; ++reg) um[a][reg] = 0.f;

        if (!(n16 & 1)) {  // even columns hold a2 -> activation, u/uh2 to LDS
            #pragma unroll
            for (int a = 0; a < 4; ++a)
                #pragma unroll
                for (int reg = 0; reg < 4; ++reg) {
                    int i    = (wave * 4 + a) * 16 + quad * 4 + reg;
                    float a2 = acc[a][reg] + b2s[i];
                    float h2 = tanhf(a2);
                    float t2 = 1.f - h2 * h2;
                    float u  = w3s[i] * t2;
                    um[a][reg] = u;
                    us [w][i] = u;
                    uhs[w][i] = u * h2;
                }
        }

        // rt2 = sum_i u_i * p_i : odd columns hold p; pull u from even neighbor
        float part = 0.f;
        #pragma unroll
        for (int a = 0; a < 4; ++a)
            #pragma unroll
            for (int reg = 0; reg < 4; ++reg) {
                float uo = __shfl_xor(um[a][reg], 1, 64);
                part = fmaf(uo, acc[a][reg], part);
            }
        part += __shfl_xor(part, 16, 64);
        part += __shfl_xor(part, 32, 64);
        if (quad == 0 && (n16 & 1)) r2s[wave][w] = part;
    }
    __syncthreads();
    if (tid < WPB)
        rt2s[tid] = r2s[0][tid] + r2s[1][tid] + r2s[2][tid] + r2s[3][tid];
    __syncthreads();   // W1s, us/uhs, rt2s ready — NO further barriers until combine

    #pragma unroll 1
    for (int ww = 0; ww < WPB; ++ww) {
        const int wg = w0 + ww;

        // t1 fragments for this walker (8 small broadcast global loads; krow-independent)
        half8 t1f[8];
        #pragma unroll
        for (int s = 0; s < 8; ++s)
            t1f[s] = *(const half8*)(t1h + (size_t)wg * HID + (s * 4 + quad) * 8);

        // u fold operands: 4 broadcast b128 reads (16 regs)
        float4v uu[4];
        #pragma unroll
        for (int a = 0; a < 4; ++a)
            uu[a] = *(const float4v*)(&us[ww][(wave * 4 + a) * 16 + quad * 4]);

        // deferred-rt1 accumulator
        float4v sq[4];
        #pragma unroll
        for (int a = 0; a < 4; ++a) sq[a] = (float4v){0.f, 0.f, 0.f, 0.f};

        #pragma unroll 1
        for (int kt = 0; kt < 3; ++kt) {
            const int krow = kt * 16 + n16;

            // conflict-free swizzled reads of walker-invariant W1 (same pattern as old AsT)
            half8 w1v[8];
            #pragma unroll
            for (int s = 0; s < 8; ++s)
                w1v[s] = *(const half8*)(W1s + krow * HID
                          + ((((s * 4 + quad) ^ (krow & 7)) << 3)));

            float4v acc[4];
            #pragma unroll
            for (int a = 0; a < 4; ++a) acc[a] = (float4v){0.f, 0.f, 0.f, 0.f};

            __builtin_amdgcn_s_setprio(1);
            #pragma unroll
            for (int s = 0; s < 8; ++s) {
                half8 bf = w1v[s] * t1f[s];   // bitwise-identical to old staged AsT product
                #pragma unroll
                for (int a = 0; a < 4; ++a)
                    acc[a] = __builtin_amdgcn_mfma_f32_16x16x32_f16(
                        afr[s][a], bf, acc[a], 0, 0, 0);
            }
            __builtin_amdgcn_s_setprio(0);

            float g = 0.f;
            #pragma unroll
            for (int a = 0; a < 4; ++a)
                #pragma unroll
                for (int reg = 0; reg < 4; ++reg) {
                    float m = acc[a][reg];
                    sq[a][reg] = fmaf(m, m, sq[a][reg]);
                    g          = fmaf(m, uu[a][reg], g);
                }
            g += __shfl_xor(g, 16, 64);
            g += __shfl_xor(g, 32, 64);
            if (lane < 16) gw[ww][wave][kt * 16 + lane] = g;
        }

        // rt1 contraction: load uh now (4 b128), fold against sq
        float rt1 = 0.f;
        #pragma unroll
        for (int a = 0; a < 4; ++a) {
            float4v uh = *(const float4v*)(&uhs[ww][(wave * 4 + a) * 16 + quad * 4]);
            #pragma unroll
            for (int reg = 0; reg < 4; ++reg)
                rt1 = fmaf(sq[a][reg], uh[reg], rt1);
        }
        rt1 += __shfl_xor(rt1, 16, 64);
        rt1 += __shfl_xor(rt1, 32, 64);
        if (lane < 16) rt1p[ww][wave][lane] = rt1;
        // no barrier: each wave writes only its own gw/rt1p slices
    }

    __syncthreads();   // all gw/rt1p durable

    // ---- deferred final combine: wave handles walkers 2*wave, 2*wave+1 ----
    const int wa = 2 * wave, wb = wa + 1;
    float rt2a = rt2s[wa];
    float rt2b = rt2s[wb];

    float r0 = rt1p[wa][quad][n16];
    float r1 = rt1p[wb][quad][n16];

    float ga = 0.f, gb = 0.f, xa = 0.f, xb = 0.f;
    if (lane < NXD) {
        ga = gw[wa][0][lane] + gw[wa][1][lane] + gw[wa][2][lane] + gw[wa][3][lane];
        gb = gw[wb][0][lane] + gw[wb][1][lane] + gw[wb][2][lane] + gw[wb][3][lane];
        xa = xs[wa][lane];
        xb = xs[wb][lane];
    }
    float gga = ga * ga, ggb = gb * gb;
    float pa = 0.5f * xa * xa, pb = 0.5f * xb * xb;
    #pragma unroll
    for (int off = 32; off > 0; off >>= 1) {
        r0  += __shfl_down(r0,  off, 64);
        r1  += __shfl_down(r1,  off, 64);
        gga += __shfl_down(gga, off, 64);
        ggb += __shfl_down(ggb, off, 64);
        pa  += __shfl_down(pa,  off, 64);
        pb  += __shfl_down(pb,  off, 64);
    }
    if (lane == 0) {
        float kina = r0 + rt2a - 0.5f * gga;
        float kinb = r1 + rt2b - 0.5f * ggb;

        float x0 = xs[wa][0], x1 = xs[wa][1], x2 = xs[wa][2];
        float x3 = xs[wa][3], x4 = xs[wa][4], x5 = xs[wa][5];
        float d01 = (x0-x1)*(x0-x1) + (x2-x1)*(x2-x1);
        float d02 = (x0-x2)*(x0-x2) + (x1-x2)*(x1-x2);
        float d12 = (x3-x5)*(x3-x5) + (x4-x5)*(x4-x5);
        float intera = GCONST * (expf(-2.f*d01) + expf(-2.f*d02) + expf(-2.f*d12));

        x0 = xs[wb][0]; x1 = xs[wb][1]; x2 = xs[wb][2];
        x3 = xs[wb][3]; x4 = xs[wb][4]; x5 = xs[wb][5];
        float e01 = (x0-x1)*(x0-x1) + (x2-x1)*(x2-x1);
        float e02 = (x0-x2)*(x0-x2) + (x1-x2)*(x1-x2);
        float e12 = (x3-x5)*(x3-x5) + (x4-x5)*(x4-x5);
        float interb = GCONST * (expf(-2.f*e01) + expf(-2.f*e02) + expf(-2.f*e12));

        const int wga = w0 + wa, wgb = w0 + wb;
        out[wga]             = kina + pa + intera;
        out[NWALK + wga]     = kina;
        out[2 * NWALK + wga] = pa;
        out[3 * NWALK + wga] = intera;
        out[wgb]             = kinb + pb + interb;
        out[NWALK + wgb]     = kinb;
        out[2 * NWALK + wgb] = pb;
        out[3 * NWALK + wgb] = interb;
    }
}

extern "C" void kernel_launch(void* const* d_in, const int* in_sizes, int n_in,
                              void* d_out, int out_size, void* d_ws, size_t ws_size,
                              hipStream_t stream) {
    const float* x  = (const float*)d_in[0];
    const float* W1 = (const float*)d_in[1];
    const float* b1 = (const float*)d_in[2];
    const float* W2 = (const float*)d_in[3];
    const float* b2 = (const float*)d_in[4];
    const float* w3 = (const float*)d_in[5];
    float* out = (float*)d_out;

    char* ws = (char*)d_ws;
    _Float16* W2c = (_Float16*)(ws);                       // 128 KB
    _Float16* W1c = (_Float16*)(ws + 131072);              // 24 KB
    _Float16* t1h = (_Float16*)(ws + 155648);              // 2 MB
    _Float16* h1h = (_Float16*)(ws + 2252800);             // 2 MB
    _Float16* chv = (_Float16*)(ws + 4349952);             // 2 MB

    prep_all<<<16 + NWALK / 16, 256, 0, stream>>>(W2, W1, x, b1, W2c, W1c, t1h, h1h, chv);
    eloc8<<<NWALK / WPB, 256, 0, stream>>>(x, b2, w3, W2c, W1c, t1h, h1h, chv, out);
}

// Round 8
// 99.482 us; speedup vs baseline: 1.3474x; 1.1092x over previous
//
#include <hip/hip_runtime.h>
#include <cmath>

#define NWALK 4096
#define NXD   48
#define HID   256
#define WPB   8
#define GCONST 0.7978845608028654f

typedef _Float16 half8   __attribute__((ext_vector_type(8)));
typedef float    float4v __attribute__((ext_vector_type(4)));

// ---------- eloc_fused: fully self-contained per block ----------
// phase 1: stage xs/b2s/w3s + fp16-swizzled W1 into LDS
// phase 2: layer-1 (identical arithmetic to old prep_all) -> t1s/h1s/chs in LDS
// phase 3: afr from W2 (f32, transposed read, same fp16 cast as old W2c)
// phase 4: prologue GEMM (a2/p) + activation -> us/uhs/rt2s
// phase 5: barrier-free walker loop (verbatim round-7 main loop, t1f from LDS)
__global__ __launch_bounds__(256, 2) void eloc_fused(
    const float* __restrict__ x,
    const float* __restrict__ W1,
    const float* __restrict__ b1,
    const float* __restrict__ W2,
    const float* __restrict__ b2,
    const float* __restrict__ w3,
    float* __restrict__ out)
{
    __shared__ __align__(16) _Float16 W1s[48 * HID];      // 24576 B, swizzled fp16 W1
    __shared__ __align__(16) _Float16 t1s[WPB][HID];      // 4096 B
    __shared__ __align__(16) _Float16 h1s[WPB][HID];      // 4096 B
    __shared__ __align__(16) _Float16 chs[WPB][HID];      // 4096 B
    __shared__ float us[WPB][HID], uhs[WPB][HID];         // 16384 B
    __shared__ float xs[WPB][NXD];                        // 1536 B
    __shared__ float gw[WPB][4][NXD];                     // 6144 B
    __shared__ float rt1p[WPB][4][16];                    // 2048 B
    __shared__ float b2s[HID], w3s[HID];                  // 2048 B
    __shared__ float r2s[4][WPB];                         // 128 B
    __shared__ float rt2s[WPB];                           // 32 B
    // total 65,184 B  (< 65,536)

    const int w0   = blockIdx.x * WPB;
    const int tid  = threadIdx.x;
    const int wave = tid >> 6;          // 0..3
    const int lane = tid & 63;
    const int n16  = lane & 15;
    const int quad = (tid >> 4) & 3;    // 0..3

    // ---- phase 1: staging ----
    b2s[tid] = b2[tid];
    w3s[tid] = w3[tid];
    #pragma unroll
    for (int t = tid; t < WPB * NXD; t += 256)
        ((float*)xs)[t] = x[w0 * NXD + t];

    // W1s: fp16 swizzled copy of W1 (identical cast to old W1c, identical swizzle to R7)
    #pragma unroll
    for (int t = tid; t < 48 * 32; t += 256) {
        int k = t >> 5, c = t & 31;
        const float* srcp = W1 + k * HID + c * 8;
        half8 hv;
        #pragma unroll
        for (int e = 0; e < 8; ++e) hv[e] = (_Float16)srcp[e];
        *(half8*)(W1s + k * HID + ((c ^ (k & 7)) * 8)) = hv;
    }

    // layer-1 column of W1 (f32) + squared norm — identical to old prep_all
    float col[NXD];
    float S = 0.f;
    #pragma unroll
    for (int k = 0; k < NXD; ++k) {
        float v = W1[k * HID + tid];
        col[k] = v;
        S = fmaf(v, v, S);
    }

    __syncthreads();   // xs ready

    // ---- phase 2: layer-1 for this block's 8 walkers (i = tid) ----
    {
        const float b = b1[tid];
        #pragma unroll
        for (int w = 0; w < WPB; ++w) {
            float a1 = b;
            #pragma unroll
            for (int k = 0; k < NXD; ++k)
                a1 = fmaf(xs[w][k], col[k], a1);
            float h1 = tanhf(a1);
            float t1 = 1.f - h1 * h1;
            t1s[w][tid] = (_Float16)t1;
            h1s[w][tid] = (_Float16)h1;
            chs[w][tid] = (_Float16)(S * h1 * t1);
        }
    }

    // ---- phase 3: afr from W2 f32 (transposed read; same fp16 values as old W2c) ----
    // col[] is dead here, freeing registers for the fragment build.
    half8 afr[8][4];
    #pragma unroll
    for (int s = 0; s < 8; ++s)
        #pragma unroll
        for (int a = 0; a < 4; ++a) {
            const int j  = (wave * 4 + a) * 16 + n16;
            const int ib = s * 32 + quad * 8;
            half8 hv;
            #pragma unroll
            for (int e = 0; e < 8; ++e)
                hv[e] = (_Float16)W2[(ib + e) * HID + j];
            afr[s][a] = hv;
        }

    __syncthreads();   // t1s/h1s/chs + W1s ready

    // ---- phase 4: prologue GEMM: a2 = W2^T h1 (even cols), p = W2^T c (odd cols) ----
    {
        const _Float16* srcb = (n16 & 1) ? &chs[0][0] : &h1s[0][0];
        const _Float16* brow = srcb + (n16 >> 1) * HID;

        float4v acc[4];
        #pragma unroll
        for (int a = 0; a < 4; ++a) acc[a] = (float4v){0.f, 0.f, 0.f, 0.f};
        #pragma unroll
        for (int s = 0; s < 8; ++s) {
            half8 bf = *(const half8*)(brow + (s * 4 + quad) * 8);
            #pragma unroll
            for (int a = 0; a < 4; ++a)
                acc[a] = __builtin_amdgcn_mfma_f32_16x16x32_f16(afr[s][a], bf, acc[a], 0, 0, 0);
        }

        const int w = n16 >> 1;
        float um[4][4];
        #pragma unroll
        for (int a = 0; a < 4; ++a)
            #pragma unroll
            for (int reg = 0; reg < 4; ++reg) um[a][reg] = 0.f;

        if (!(n16 & 1)) {  // even columns hold a2 -> activation, u/uh2 to LDS
            #pragma unroll
            for (int a = 0; a < 4; ++a)
                #pragma unroll
                for (int reg = 0; reg < 4; ++reg) {
                    int i    = (wave * 4 + a) * 16 + quad * 4 + reg;
                    float a2 = acc[a][reg] + b2s[i];
                    float h2 = tanhf(a2);
                    float t2 = 1.f - h2 * h2;
                    float u  = w3s[i] * t2;
                    um[a][reg] = u;
                    us [w][i] = u;
                    uhs[w][i] = u * h2;
                }
        }

        // rt2 = sum_i u_i * p_i : odd columns hold p; pull u from even neighbor
        float part = 0.f;
        #pragma unroll
        for (int a = 0; a < 4; ++a)
            #pragma unroll
            for (int reg = 0; reg < 4; ++reg) {
                float uo = __shfl_xor(um[a][reg], 1, 64);
                part = fmaf(uo, acc[a][reg], part);
            }
        part += __shfl_xor(part, 16, 64);
        part += __shfl_xor(part, 32, 64);
        if (quad == 0 && (n16 & 1)) r2s[wave][w] = part;
    }
    __syncthreads();
    if (tid < WPB)
        rt2s[tid] = r2s[0][tid] + r2s[1][tid] + r2s[2][tid] + r2s[3][tid];
    __syncthreads();   // us/uhs, rt2s ready — NO further barriers until combine

    // ---- phase 5: barrier-free walker loop (verbatim R7; t1f now from LDS) ----
    #pragma unroll 1
    for (int ww = 0; ww < WPB; ++ww) {
        // t1 fragments for this walker: 8 broadcast LDS reads (krow-independent)
        half8 t1f[8];
        #pragma unroll
        for (int s = 0; s < 8; ++s)
            t1f[s] = *(const half8*)(&t1s[ww][(s * 4 + quad) * 8]);

        // u fold operands: 4 broadcast b128 reads (16 regs)
        float4v uu[4];
        #pragma unroll
        for (int a = 0; a < 4; ++a)
            uu[a] = *(const float4v*)(&us[ww][(wave * 4 + a) * 16 + quad * 4]);

        // deferred-rt1 accumulator
        float4v sq[4];
        #pragma unroll
        for (int a = 0; a < 4; ++a) sq[a] = (float4v){0.f, 0.f, 0.f, 0.f};

        #pragma unroll 1
        for (int kt = 0; kt < 3; ++kt) {
            const int krow = kt * 16 + n16;

            // conflict-free swizzled reads of walker-invariant W1
            half8 w1v[8];
            #pragma unroll
            for (int s = 0; s < 8; ++s)
                w1v[s] = *(const half8*)(W1s + krow * HID
                          + ((((s * 4 + quad) ^ (krow & 7)) << 3)));

            float4v acc[4];
            #pragma unroll
            for (int a = 0; a < 4; ++a) acc[a] = (float4v){0.f, 0.f, 0.f, 0.f};

            __builtin_amdgcn_s_setprio(1);
            #pragma unroll
            for (int s = 0; s < 8; ++s) {
                half8 bf = w1v[s] * t1f[s];   // bitwise-identical to old staged product
                #pragma unroll
                for (int a = 0; a < 4; ++a)
                    acc[a] = __builtin_amdgcn_mfma_f32_16x16x32_f16(
                        afr[s][a], bf, acc[a], 0, 0, 0);
            }
            __builtin_amdgcn_s_setprio(0);

            float g = 0.f;
            #pragma unroll
            for (int a = 0; a < 4; ++a)
                #pragma unroll
                for (int reg = 0; reg < 4; ++reg) {
                    float m = acc[a][reg];
                    sq[a][reg] = fmaf(m, m, sq[a][reg]);
                    g          = fmaf(m, uu[a][reg], g);
                }
            g += __shfl_xor(g, 16, 64);
            g += __shfl_xor(g, 32, 64);
            if (lane < 16) gw[ww][wave][kt * 16 + lane] = g;
        }

        // rt1 contraction: load uh now (4 b128), fold against sq
        float rt1 = 0.f;
        #pragma unroll
        for (int a = 0; a < 4; ++a) {
            float4v uh = *(const float4v*)(&uhs[ww][(wave * 4 + a) * 16 + quad * 4]);
            #pragma unroll
            for (int reg = 0; reg < 4; ++reg)
                rt1 = fmaf(sq[a][reg], uh[reg], rt1);
        }
        rt1 += __shfl_xor(rt1, 16, 64);
        rt1 += __shfl_xor(rt1, 32, 64);
        if (lane < 16) rt1p[ww][wave][lane] = rt1;
        // no barrier: each wave writes only its own gw/rt1p slices
    }

    __syncthreads();   // all gw/rt1p durable

    // ---- deferred final combine: wave handles walkers 2*wave, 2*wave+1 ----
    const int wa = 2 * wave, wb = wa + 1;
    float rt2a = rt2s[wa];
    float rt2b = rt2s[wb];

    float r0 = rt1p[wa][quad][n16];
    float r1 = rt1p[wb][quad][n16];

    float ga = 0.f, gb = 0.f, xa = 0.f, xb = 0.f;
    if (lane < NXD) {
        ga = gw[wa][0][lane] + gw[wa][1][lane] + gw[wa][2][lane] + gw[wa][3][lane];
        gb = gw[wb][0][lane] + gw[wb][1][lane] + gw[wb][2][lane] + gw[wb][3][lane];
        xa = xs[wa][lane];
        xb = xs[wb][lane];
    }
    float gga = ga * ga, ggb = gb * gb;
    float pa = 0.5f * xa * xa, pb = 0.5f * xb * xb;
    #pragma unroll
    for (int off = 32; off > 0; off >>= 1) {
        r0  += __shfl_down(r0,  off, 64);
        r1  += __shfl_down(r1,  off, 64);
        gga += __shfl_down(gga, off, 64);
        ggb += __shfl_down(ggb, off, 64);
        pa  += __shfl_down(pa,  off, 64);
        pb  += __shfl_down(pb,  off, 64);
    }
    if (lane == 0) {
        float kina = r0 + rt2a - 0.5f * gga;
        float kinb = r1 + rt2b - 0.5f * ggb;

        float x0 = xs[wa][0], x1 = xs[wa][1], x2 = xs[wa][2];
        float x3 = xs[wa][3], x4 = xs[wa][4], x5 = xs[wa][5];
        float d01 = (x0-x1)*(x0-x1) + (x2-x1)*(x2-x1);
        float d02 = (x0-x2)*(x0-x2) + (x1-x2)*(x1-x2);
        float d12 = (x3-x5)*(x3-x5) + (x4-x5)*(x4-x5);
        float intera = GCONST * (expf(-2.f*d01) + expf(-2.f*d02) + expf(-2.f*d12));

        x0 = xs[wb][0]; x1 = xs[wb][1]; x2 = xs[wb][2];
        x3 = xs[wb][3]; x4 = xs[wb][4]; x5 = xs[wb][5];
        float e01 = (x0-x1)*(x0-x1) + (x2-x1)*(x2-x1);
        float e02 = (x0-x2)*(x0-x2) + (x1-x2)*(x1-x2);
        float e12 = (x3-x5)*(x3-x5) + (x4-x5)*(x4-x5);
        float interb = GCONST * (expf(-2.f*e01) + expf(-2.f*e02) + expf(-2.f*e12));

        const int wga = w0 + wa, wgb = w0 + wb;
        out[wga]             = kina + pa + intera;
        out[NWALK + wga]     = kina;
        out[2 * NWALK + wga] = pa;
        out[3 * NWALK + wga] = intera;
        out[wgb]             = kinb + pb + interb;
        out[NWALK + wgb]     = kinb;
        out[2 * NWALK + wgb] = pb;
        out[3 * NWALK + wgb] = interb;
    }
}

extern "C" void kernel_launch(void* const* d_in, const int* in_sizes, int n_in,
                              void* d_out, int out_size, void* d_ws, size_t ws_size,
                              hipStream_t stream) {
    const float* x  = (const float*)d_in[0];
    const float* W1 = (const float*)d_in[1];
    const float* b1 = (const float*)d_in[2];
    const float* W2 = (const float*)d_in[3];
    const float* b2 = (const float*)d_in[4];
    const float* w3 = (const float*)d_in[5];
    float* out = (float*)d_out;

    // single fused launch; workspace unused
    eloc_fused<<<NWALK / WPB, 256, 0, stream>>>(x, W1, b1, W2, b2, w3, out);
}